// Round 4
// baseline (200.880 us; speedup 1.0000x reference)
//
#include <hip/hip_runtime.h>
#include <hip/hip_bf16.h>

typedef unsigned short u16;
typedef __attribute__((ext_vector_type(4))) float f32x4;
typedef __attribute__((ext_vector_type(16))) float f32x16;
typedef __attribute__((ext_vector_type(8))) short short8;
typedef __attribute__((ext_vector_type(8))) unsigned short ushort8;

__device__ __forceinline__ u16 f2bf(float f) {
  union { float f; unsigned u; } v; v.f = f;
  unsigned r = v.u + 0x7fffu + ((v.u >> 16) & 1u);
  return (u16)(r >> 16);
}
__device__ __forceinline__ float b2f(u16 h) {
  union { unsigned u; float f; } v; v.u = ((unsigned)h) << 16;
  return v.f;
}
__device__ __forceinline__ f32x4 mfma16(short8 a, short8 b, f32x4 c) {
  return __builtin_amdgcn_mfma_f32_16x16x32_bf16(a, b, c, 0, 0, 0);
}
__device__ __forceinline__ f32x16 mfma32(short8 a, short8 b, f32x16 c) {
  return __builtin_amdgcn_mfma_f32_32x32x16_bf16(a, b, c, 0, 0, 0);
}
__device__ __forceinline__ unsigned cvtpk(float a, float b) {
  unsigned r;
  asm("v_cvt_pk_bf16_f32 %0, %1, %2" : "=v"(r) : "v"(a), "v"(b));
  return r;
}
__device__ __forceinline__ short8 pack4(unsigned w0, unsigned w1, unsigned w2, unsigned w3) {
  union { unsigned u[4]; short8 s; } t;
  t.u[0] = w0; t.u[1] = w1; t.u[2] = w2; t.u[3] = w3;
  return t.s;
}
__device__ __forceinline__ float exp2h(float x) { return __builtin_amdgcn_exp2f(x); }

// ---------------- prep: fp32 -> bf16 convert ----------------
__global__ __launch_bounds__(256) void cvt_f32_bf16_k(const float* __restrict__ in,
                                                      u16* __restrict__ out, int n8) {
  int t = blockIdx.x * 256 + threadIdx.x;
  if (t >= n8) return;
  const float4* p = (const float4*)(in + (size_t)t * 8);
  float4 a = p[0], b = p[1];
  ushort8 o;
  o[0] = f2bf(a.x); o[1] = f2bf(a.y); o[2] = f2bf(a.z); o[3] = f2bf(a.w);
  o[4] = f2bf(b.x); o[5] = f2bf(b.y); o[6] = f2bf(b.z); o[7] = f2bf(b.w);
  *(ushort8*)(out + (size_t)t * 8) = o;
}

// ---------------- prep: transpose fp32 [R][C] -> bf16 [C][R] ----------------
__global__ __launch_bounds__(256) void transpose_f32_bf16_k(const float* __restrict__ in,
                                                            u16* __restrict__ out, int R, int C) {
  __shared__ float tile[32][33];
  int bc = blockIdx.x * 32, br = blockIdx.y * 32;
  int tx = threadIdx.x & 31, ty = threadIdx.x >> 5;
#pragma unroll
  for (int p = 0; p < 4; ++p)
    tile[ty + p * 8][tx] = in[(size_t)(br + ty + p * 8) * C + bc + tx];
  __syncthreads();
#pragma unroll
  for (int p = 0; p < 4; ++p)
    out[(size_t)(bc + ty + p * 8) * R + br + tx] = f2bf(tile[tx][ty + p * 8]);
}

// ---------------- GEMM (m97 structure): C[M][N] = A[M][K=1024] * Bt[N][K=1024]^T ----------------
template <int MODE>
__global__ __launch_bounds__(256) void gemm_bt_k(const u16* __restrict__ A,
                                                 const u16* __restrict__ Bt,
                                                 const float* __restrict__ bias,
                                                 void* __restrict__ Cout) {
  __shared__ __align__(16) u16 As[128 * 32];
  __shared__ __align__(16) u16 Bs[128 * 32];
  const int tid = threadIdx.x, lane = tid & 63, w = tid >> 6;
  const int wr = w >> 1, wc = w & 1, g = lane >> 4, c16 = lane & 15;
  const int rowBase = blockIdx.y * 128, colBase = blockIdx.x * 128;
  f32x4 acc[4][4] = {};
  const int e0 = (w * 2 + 0) * 512 + lane * 8;
  const int e1 = (w * 2 + 1) * 512 + lane * 8;
  const u16* Ag0 = A + (size_t)(rowBase + (e0 >> 5)) * 1024 + (e0 & 31);
  const u16* Ag1 = A + (size_t)(rowBase + (e1 >> 5)) * 1024 + (e1 & 31);
  const u16* Bg0 = Bt + (size_t)(colBase + (e0 >> 5)) * 1024 + (e0 & 31);
  const u16* Bg1 = Bt + (size_t)(colBase + (e1 >> 5)) * 1024 + (e1 & 31);
  u16* As0 = As + (w * 2 + 0) * 512;
  u16* As1 = As + (w * 2 + 1) * 512;
  u16* Bs0 = Bs + (w * 2 + 0) * 512;
  u16* Bs1 = Bs + (w * 2 + 1) * 512;
  for (int k0 = 0; k0 < 1024; k0 += 32) {
    __builtin_amdgcn_global_load_lds((const __attribute__((address_space(1))) void*)(Ag0 + k0),
                                     (__attribute__((address_space(3))) void*)As0, 16, 0, 0);
    __builtin_amdgcn_global_load_lds((const __attribute__((address_space(1))) void*)(Ag1 + k0),
                                     (__attribute__((address_space(3))) void*)As1, 16, 0, 0);
    __builtin_amdgcn_global_load_lds((const __attribute__((address_space(1))) void*)(Bg0 + k0),
                                     (__attribute__((address_space(3))) void*)Bs0, 16, 0, 0);
    __builtin_amdgcn_global_load_lds((const __attribute__((address_space(1))) void*)(Bg1 + k0),
                                     (__attribute__((address_space(3))) void*)Bs1, 16, 0, 0);
    asm volatile("s_waitcnt vmcnt(0)" ::: "memory");
    __syncthreads();
    short8 af[4], bfr[4];
#pragma unroll
    for (int t = 0; t < 4; ++t)
      af[t] = *(const short8*)(As + ((wr * 64 + t * 16 + c16) * 32 + g * 8));
#pragma unroll
    for (int t = 0; t < 4; ++t)
      bfr[t] = *(const short8*)(Bs + ((wc * 64 + t * 16 + c16) * 32 + g * 8));
#pragma unroll
    for (int i = 0; i < 4; ++i)
#pragma unroll
      for (int j = 0; j < 4; ++j) acc[i][j] = mfma16(af[i], bfr[j], acc[i][j]);
    __syncthreads();
  }
#pragma unroll
  for (int i = 0; i < 4; ++i) {
    int mbase = rowBase + wr * 64 + i * 16 + 4 * g;
#pragma unroll
    for (int j = 0; j < 4; ++j) {
      int n = colBase + wc * 64 + j * 16 + c16;
      float bv = bias[n];
#pragma unroll
      for (int r = 0; r < 4; ++r) {
        float v = acc[i][j][r] + bv;
        int m = mbase + r;
        if (MODE == 0) {
          int which = n >> 10, hh = (n >> 6) & 15, d = n & 63;
          int bb = m >> 11, s = m & 2047;
          ((u16*)Cout)[((size_t)(((which * 2 + bb) * 16 + hh) * 2048 + s) << 6) + d] = f2bf(v);
        } else {
          ((float*)Cout)[(size_t)m * 1024 + n] = v;
        }
      }
    }
  }
}

// ---------------- RoPE in place on Q and K; Q additionally pre-scaled by 0.125*log2(e) ----------------
__global__ __launch_bounds__(256) void rope_k(u16* __restrict__ qk, const float* __restrict__ cosT,
                                              const float* __restrict__ sinT, int npairs) {
  int p = blockIdx.x * 256 + threadIdx.x;
  if (p >= npairs) return;
  size_t E = (size_t)p * 2;
  int i = (int)((E >> 1) & 31);
  int s = (int)((E >> 6) & 2047);
  const float qs = (p < 2097152) ? 0.18033688f : 1.0f;  // 0.125 * log2(e) on Q slab
  u16* ptr = qk + E;
  float xe = b2f(ptr[0]), xo = b2f(ptr[1]);
  float c = cosT[s * 32 + i], sn = sinT[s * 32 + i];
  ptr[0] = f2bf((xe * c - xo * sn) * qs);
  ptr[1] = f2bf((xe * sn + xo * c) * qs);
}

// ---------------- V [bh][s][64] -> Vt [bh][64][s] (bf16) ----------------
__global__ __launch_bounds__(256) void vtrans_k(const u16* __restrict__ V, u16* __restrict__ Vt) {
  __shared__ u16 t[64][72];
  const int bh = blockIdx.y, s0 = blockIdx.x * 64;
  const u16* src = V + ((size_t)bh << 17);
  u16* dst = Vt + ((size_t)bh << 17);
  const int r = threadIdx.x >> 2, c0 = (threadIdx.x & 3) * 16;
  *(short8*)&t[r][c0] = *(const short8*)(src + (size_t)(s0 + r) * 64 + c0);
  *(short8*)&t[r][c0 + 8] = *(const short8*)(src + (size_t)(s0 + r) * 64 + c0 + 8);
  __syncthreads();
  const int d = threadIdx.x >> 2, sc0 = (threadIdx.x & 3) * 16;
  ushort8 o0, o1;
#pragma unroll
  for (int e = 0; e < 8; ++e) { o0[e] = t[sc0 + e][d]; o1[e] = t[sc0 + 8 + e][d]; }
  *(ushort8*)(dst + (size_t)d * 2048 + s0 + sc0) = o0;
  *(ushort8*)(dst + (size_t)d * 2048 + s0 + sc0 + 8) = o1;
}

// ---------------- Flash attention v3: LDS-free, 32x32 swapped QK^T, in-register P ----------------
// One wave = 32 q-rows x full kv sweep (tiles of 64). No barriers, no LDS.
// wave-unit wu: bh = wu & 31 (4 heads per XCD), mt = 63 - wu/32 (LPT), qb = 32*mt.
// Q pre-scaled by 0.125*log2e -> softmax in exp2 domain. Defer-max THR = 11.5 (=8 nats).
__global__ __launch_bounds__(256, 4) void attn3_k(const u16* __restrict__ Qm,
                                                  const u16* __restrict__ Km,
                                                  const u16* __restrict__ Vtm,
                                                  u16* __restrict__ Om) {
  const int lane = threadIdx.x & 63;
  const int wu = blockIdx.x * 4 + (threadIdx.x >> 6);
  const int bh = wu & 31;
  const int mt = 63 - (wu >> 5);
  const int b = bh >> 4, hd = bh & 15;
  const int qb = mt * 32;
  const int q32 = lane & 31, h = lane >> 5;

  const u16* Qp = Qm + ((size_t)bh << 17);
  const u16* Kp = Km + ((size_t)bh << 17);
  const u16* Vtp = Vtm + ((size_t)bh << 17);

  // Q fragments (B-operand): lane holds Q[qb+q32][16ks + 8h .. +7]
  const u16* qrow = Qp + ((size_t)(qb + q32) << 6) + 8 * h;
  short8 qf[4];
#pragma unroll
  for (int ks = 0; ks < 4; ++ks) qf[ks] = *(const short8*)(qrow + 16 * ks);

  f32x16 acc0 = {}, acc1 = {};
  float m_run = -1e30f, l_run = 0.f;
  const int NT = (mt >> 1) + 1;
  const int qg = qb + q32;

  for (int kt = 0; kt < NT; ++kt) {
    const int k0 = kt * 64;
    const u16* kbase = Kp + (((size_t)k0 << 6) + 8 * h);

    // ---- QK^T swapped: s0 = S[kv 0..31][q], s1 = S[kv 32..63][q] (pre-scaled, log2 domain)
    f32x16 s0 = {}, s1 = {};
    __builtin_amdgcn_s_setprio(1);
#pragma unroll
    for (int ks = 0; ks < 4; ++ks) {
      short8 kf = *(const short8*)(kbase + ((size_t)q32 << 6) + 16 * ks);
      s0 = mfma32(kf, qf[ks], s0);
    }
#pragma unroll
    for (int ks = 0; ks < 4; ++ks) {
      short8 kf = *(const short8*)(kbase + ((size_t)(32 + q32) << 6) + 16 * ks);
      s1 = mfma32(kf, qf[ks], s1);
    }
    __builtin_amdgcn_s_setprio(0);

    // ---- causal mask on diagonal tile
    if (kt == NT - 1) {
#pragma unroll
      for (int r = 0; r < 16; ++r) {
        const int kvl = k0 + (r & 3) + 8 * (r >> 2) + 4 * h;
        s0[r] = (kvl <= qg) ? s0[r] : -1e30f;
        s1[r] = (kvl + 32 <= qg) ? s1[r] : -1e30f;
      }
    }

    // ---- online softmax (per-lane row q; lane pair L/L+32 holds kv halves)
    float pmax = s0[0];
#pragma unroll
    for (int r = 1; r < 16; ++r) pmax = fmaxf(pmax, s0[r]);
#pragma unroll
    for (int r = 0; r < 16; ++r) pmax = fmaxf(pmax, s1[r]);
    pmax = fmaxf(pmax, __shfl_xor(pmax, 32));

    if (!__all(pmax <= m_run + 11.5f)) {   // rescale path (rare: first tile + max growth)
      const float mn = fmaxf(m_run, pmax);
      const float alpha = exp2h(m_run - mn);
      l_run *= alpha;
      m_run = mn;
#pragma unroll
      for (int r = 0; r < 16; ++r) {
        const int row = (r & 3) + 8 * (r >> 2) + 4 * h;
        const float ar = __shfl(alpha, row);
        acc0[r] *= ar; acc1[r] *= ar;
      }
    }

    float rs = 0.f;
#pragma unroll
    for (int r = 0; r < 16; ++r) { s0[r] = exp2h(s0[r] - m_run); rs += s0[r]; }
#pragma unroll
    for (int r = 0; r < 16; ++r) { s1[r] = exp2h(s1[r] - m_run); rs += s1[r]; }
    rs += __shfl_xor(rs, 32);
    l_run += rs;

    // ---- P -> A-fragments in-register (cvt_pk + lane32 exchange)
    short8 pa[4];
#pragma unroll
    for (int t = 0; t < 2; ++t) {
      float p0, p1, p2, p3, p4, p5, p6, p7, p8, p9, pa_, pb_, pc_, pd_, pe_, pf_;
      if (t == 0) {
        p0 = s0[0];  p1 = s0[1];  p2 = s0[2];  p3 = s0[3];
        p4 = s0[4];  p5 = s0[5];  p6 = s0[6];  p7 = s0[7];
        p8 = s0[8];  p9 = s0[9];  pa_ = s0[10]; pb_ = s0[11];
        pc_ = s0[12]; pd_ = s0[13]; pe_ = s0[14]; pf_ = s0[15];
      } else {
        p0 = s1[0];  p1 = s1[1];  p2 = s1[2];  p3 = s1[3];
        p4 = s1[4];  p5 = s1[5];  p6 = s1[6];  p7 = s1[7];
        p8 = s1[8];  p9 = s1[9];  pa_ = s1[10]; pb_ = s1[11];
        pc_ = s1[12]; pd_ = s1[13]; pe_ = s1[14]; pf_ = s1[15];
      }
      const unsigned a0 = cvtpk(p0, p1), a1 = cvtpk(p2, p3);
      const unsigned a2 = cvtpk(p4, p5), a3 = cvtpk(p6, p7);
      const unsigned b0 = cvtpk(p8, p9), b1 = cvtpk(pa_, pb_);
      const unsigned b2 = cvtpk(pc_, pd_), b3 = cvtpk(pe_, pf_);
      const unsigned r0 = __shfl_xor(h ? a0 : a2, 32);
      const unsigned r1 = __shfl_xor(h ? a1 : a3, 32);
      pa[2 * t] = h ? pack4(r0, r1, a2, a3) : pack4(a0, a1, r0, r1);
      const unsigned r2 = __shfl_xor(h ? b0 : b2, 32);
      const unsigned r3 = __shfl_xor(h ? b1 : b3, 32);
      pa[2 * t + 1] = h ? pack4(r2, r3, b2, b3) : pack4(b0, b1, r2, r3);
    }

    // ---- PV: acc[c] += P[q][kv16] * Vt-frag
    const u16* vbase = Vtp + k0 + 8 * h;
    __builtin_amdgcn_s_setprio(1);
#pragma unroll
    for (int ks = 0; ks < 4; ++ks) {
      short8 vf0 = *(const short8*)(vbase + (size_t)q32 * 2048 + 16 * ks);
      short8 vf1 = *(const short8*)(vbase + (size_t)(32 + q32) * 2048 + 16 * ks);
      acc0 = mfma32(pa[ks], vf0, acc0);
      acc1 = mfma32(pa[ks], vf1, acc1);
    }
    __builtin_amdgcn_s_setprio(0);
  }

  // ---- epilogue: divide by l (per-row broadcast) and store
#pragma unroll
  for (int r = 0; r < 16; ++r) {
    const int row = (r & 3) + 8 * (r >> 2) + 4 * h;
    const float li = 1.0f / __shfl(l_run, row);
    const int q = qb + row;
    const size_t base = ((size_t)(b * 2048 + q) << 10) + hd * 64 + q32;
    Om[base] = f2bf(acc0[r] * li);
    Om[base + 32] = f2bf(acc1[r] * li);
  }
}

extern "C" void kernel_launch(void* const* d_in, const int* in_sizes, int n_in,
                              void* d_out, int out_size, void* d_ws, size_t ws_size,
                              hipStream_t stream) {
  const float* x        = (const float*)d_in[0];
  const float* rope_cos = (const float*)d_in[1];
  const float* rope_sin = (const float*)d_in[2];
  const float* Wqkv     = (const float*)d_in[3];
  const float* bqkv     = (const float*)d_in[4];
  const float* Wout     = (const float*)d_in[5];
  const float* bout     = (const float*)d_in[6];
  float* out = (float*)d_out;
  char* ws = (char*)d_ws;

  u16* Xb      = (u16*)(ws);                  //  8,388,608 B : x bf16 [4096][1024]
  u16* WqkvT   = (u16*)(ws + 8388608);        //  6,291,456 B : Wqkv^T bf16
  u16* WoutT   = (u16*)(ws + 14680064);       //  2,097,152 B : Wout^T bf16
  u16* QKV     = (u16*)(ws + 16777216);       // 25,165,824 B : [3][2][16][2048][64]
  u16* AttnOut = (u16*)(ws + 41943040);       //  8,388,608 B : [4096][1024] bf16
  u16* Vt      = (u16*)(ws + 50331648);       //  8,388,608 B : [32][64][2048] bf16

  cvt_f32_bf16_k<<<dim3(2048), dim3(256), 0, stream>>>(x, Xb, 524288);
  transpose_f32_bf16_k<<<dim3(96, 32), dim3(256), 0, stream>>>(Wqkv, WqkvT, 1024, 3072);
  transpose_f32_bf16_k<<<dim3(32, 32), dim3(256), 0, stream>>>(Wout, WoutT, 1024, 1024);

  gemm_bt_k<0><<<dim3(24, 32), dim3(256), 0, stream>>>(Xb, WqkvT, bqkv, (void*)QKV);

  rope_k<<<dim3(16384), dim3(256), 0, stream>>>(QKV, rope_cos, rope_sin, 4194304);

  u16* Qw = QKV;
  u16* Kw = QKV + (size_t)4194304;
  u16* Vw = QKV + (size_t)8388608;
  vtrans_k<<<dim3(32, 32), dim3(256), 0, stream>>>(Vw, Vt);
  attn3_k<<<dim3(512), dim3(256), 0, stream>>>(Qw, Kw, Vt, AttnOut);

  gemm_bt_k<1><<<dim3(8, 32), dim3(256), 0, stream>>>(AttnOut, WoutT, bout, out);
}

// Round 5
// 196.914 us; speedup vs baseline: 1.0201x; 1.0201x over previous
//
#include <hip/hip_runtime.h>
#include <hip/hip_bf16.h>

typedef unsigned short u16;
typedef __attribute__((ext_vector_type(4))) float f32x4;
typedef __attribute__((ext_vector_type(16))) float f32x16;
typedef __attribute__((ext_vector_type(8))) short short8;
typedef __attribute__((ext_vector_type(8))) unsigned short ushort8;

__device__ __forceinline__ u16 f2bf(float f) {
  union { float f; unsigned u; } v; v.f = f;
  unsigned r = v.u + 0x7fffu + ((v.u >> 16) & 1u);
  return (u16)(r >> 16);
}
__device__ __forceinline__ float b2f(u16 h) {
  union { unsigned u; float f; } v; v.u = ((unsigned)h) << 16;
  return v.f;
}
__device__ __forceinline__ f32x4 mfma16(short8 a, short8 b, f32x4 c) {
  return __builtin_amdgcn_mfma_f32_16x16x32_bf16(a, b, c, 0, 0, 0);
}
__device__ __forceinline__ f32x16 mfma32(short8 a, short8 b, f32x16 c) {
  return __builtin_amdgcn_mfma_f32_32x32x16_bf16(a, b, c, 0, 0, 0);
}
__device__ __forceinline__ unsigned cvtpk(float a, float b) {
  unsigned r;
  asm("v_cvt_pk_bf16_f32 %0, %1, %2" : "=v"(r) : "v"(a), "v"(b));
  return r;
}
__device__ __forceinline__ short8 pack4(unsigned w0, unsigned w1, unsigned w2, unsigned w3) {
  union { unsigned u[4]; short8 s; } t;
  t.u[0] = w0; t.u[1] = w1; t.u[2] = w2; t.u[3] = w3;
  return t.s;
}
__device__ __forceinline__ float exp2h(float x) { return __builtin_amdgcn_exp2f(x); }

// ---------------- prep: fp32 -> bf16 convert ----------------
__global__ __launch_bounds__(256) void cvt_f32_bf16_k(const float* __restrict__ in,
                                                      u16* __restrict__ out, int n8) {
  int t = blockIdx.x * 256 + threadIdx.x;
  if (t >= n8) return;
  const float4* p = (const float4*)(in + (size_t)t * 8);
  float4 a = p[0], b = p[1];
  ushort8 o;
  o[0] = f2bf(a.x); o[1] = f2bf(a.y); o[2] = f2bf(a.z); o[3] = f2bf(a.w);
  o[4] = f2bf(b.x); o[5] = f2bf(b.y); o[6] = f2bf(b.z); o[7] = f2bf(b.w);
  *(ushort8*)(out + (size_t)t * 8) = o;
}

// ---------------- prep: transpose fp32 [R][C] -> bf16 [C][R] ----------------
__global__ __launch_bounds__(256) void transpose_f32_bf16_k(const float* __restrict__ in,
                                                            u16* __restrict__ out, int R, int C) {
  __shared__ float tile[32][33];
  int bc = blockIdx.x * 32, br = blockIdx.y * 32;
  int tx = threadIdx.x & 31, ty = threadIdx.x >> 5;
#pragma unroll
  for (int p = 0; p < 4; ++p)
    tile[ty + p * 8][tx] = in[(size_t)(br + ty + p * 8) * C + bc + tx];
  __syncthreads();
#pragma unroll
  for (int p = 0; p < 4; ++p)
    out[(size_t)(bc + ty + p * 8) * R + br + tx] = f2bf(tile[tx][ty + p * 8]);
}

// ---------------- GEMM (m97 structure): C[M][N] = A[M][K=1024] * Bt[N][K=1024]^T ----------------
template <int MODE>
__global__ __launch_bounds__(256) void gemm_bt_k(const u16* __restrict__ A,
                                                 const u16* __restrict__ Bt,
                                                 const float* __restrict__ bias,
                                                 void* __restrict__ Cout) {
  __shared__ __align__(16) u16 As[128 * 32];
  __shared__ __align__(16) u16 Bs[128 * 32];
  const int tid = threadIdx.x, lane = tid & 63, w = tid >> 6;
  const int wr = w >> 1, wc = w & 1, g = lane >> 4, c16 = lane & 15;
  const int rowBase = blockIdx.y * 128, colBase = blockIdx.x * 128;
  f32x4 acc[4][4] = {};
  const int e0 = (w * 2 + 0) * 512 + lane * 8;
  const int e1 = (w * 2 + 1) * 512 + lane * 8;
  const u16* Ag0 = A + (size_t)(rowBase + (e0 >> 5)) * 1024 + (e0 & 31);
  const u16* Ag1 = A + (size_t)(rowBase + (e1 >> 5)) * 1024 + (e1 & 31);
  const u16* Bg0 = Bt + (size_t)(colBase + (e0 >> 5)) * 1024 + (e0 & 31);
  const u16* Bg1 = Bt + (size_t)(colBase + (e1 >> 5)) * 1024 + (e1 & 31);
  u16* As0 = As + (w * 2 + 0) * 512;
  u16* As1 = As + (w * 2 + 1) * 512;
  u16* Bs0 = Bs + (w * 2 + 0) * 512;
  u16* Bs1 = Bs + (w * 2 + 1) * 512;
  for (int k0 = 0; k0 < 1024; k0 += 32) {
    __builtin_amdgcn_global_load_lds((const __attribute__((address_space(1))) void*)(Ag0 + k0),
                                     (__attribute__((address_space(3))) void*)As0, 16, 0, 0);
    __builtin_amdgcn_global_load_lds((const __attribute__((address_space(1))) void*)(Ag1 + k0),
                                     (__attribute__((address_space(3))) void*)As1, 16, 0, 0);
    __builtin_amdgcn_global_load_lds((const __attribute__((address_space(1))) void*)(Bg0 + k0),
                                     (__attribute__((address_space(3))) void*)Bs0, 16, 0, 0);
    __builtin_amdgcn_global_load_lds((const __attribute__((address_space(1))) void*)(Bg1 + k0),
                                     (__attribute__((address_space(3))) void*)Bs1, 16, 0, 0);
    asm volatile("s_waitcnt vmcnt(0)" ::: "memory");
    __syncthreads();
    short8 af[4], bfr[4];
#pragma unroll
    for (int t = 0; t < 4; ++t)
      af[t] = *(const short8*)(As + ((wr * 64 + t * 16 + c16) * 32 + g * 8));
#pragma unroll
    for (int t = 0; t < 4; ++t)
      bfr[t] = *(const short8*)(Bs + ((wc * 64 + t * 16 + c16) * 32 + g * 8));
#pragma unroll
    for (int i = 0; i < 4; ++i)
#pragma unroll
      for (int j = 0; j < 4; ++j) acc[i][j] = mfma16(af[i], bfr[j], acc[i][j]);
    __syncthreads();
  }
#pragma unroll
  for (int i = 0; i < 4; ++i) {
    int mbase = rowBase + wr * 64 + i * 16 + 4 * g;
#pragma unroll
    for (int j = 0; j < 4; ++j) {
      int n = colBase + wc * 64 + j * 16 + c16;
      float bv = bias[n];
#pragma unroll
      for (int r = 0; r < 4; ++r) {
        float v = acc[i][j][r] + bv;
        int m = mbase + r;
        if (MODE == 0) {
          int which = n >> 10, hh = (n >> 6) & 15, d = n & 63;
          int bb = m >> 11, s = m & 2047;
          ((u16*)Cout)[((size_t)(((which * 2 + bb) * 16 + hh) * 2048 + s) << 6) + d] = f2bf(v);
        } else {
          ((float*)Cout)[(size_t)m * 1024 + n] = v;
        }
      }
    }
  }
}

// ---------------- RoPE in place on Q and K; Q additionally pre-scaled by 0.125*log2(e) ----------------
__global__ __launch_bounds__(256) void rope_k(u16* __restrict__ qk, const float* __restrict__ cosT,
                                              const float* __restrict__ sinT, int npairs) {
  int p = blockIdx.x * 256 + threadIdx.x;
  if (p >= npairs) return;
  size_t E = (size_t)p * 2;
  int i = (int)((E >> 1) & 31);
  int s = (int)((E >> 6) & 2047);
  const float qs = (p < 2097152) ? 0.18033688f : 1.0f;  // 0.125 * log2(e) on Q slab
  u16* ptr = qk + E;
  float xe = b2f(ptr[0]), xo = b2f(ptr[1]);
  float c = cosT[s * 32 + i], sn = sinT[s * 32 + i];
  ptr[0] = f2bf((xe * c - xo * sn) * qs);
  ptr[1] = f2bf((xe * sn + xo * c) * qs);
}

// ---------------- V [bh][s][64] -> Vt [bh][64][s] (bf16) ----------------
__global__ __launch_bounds__(256) void vtrans_k(const u16* __restrict__ V, u16* __restrict__ Vt) {
  __shared__ u16 t[64][72];
  const int bh = blockIdx.y, s0 = blockIdx.x * 64;
  const u16* src = V + ((size_t)bh << 17);
  u16* dst = Vt + ((size_t)bh << 17);
  const int r = threadIdx.x >> 2, c0 = (threadIdx.x & 3) * 16;
  *(short8*)&t[r][c0] = *(const short8*)(src + (size_t)(s0 + r) * 64 + c0);
  *(short8*)&t[r][c0 + 8] = *(const short8*)(src + (size_t)(s0 + r) * 64 + c0 + 8);
  __syncthreads();
  const int d = threadIdx.x >> 2, sc0 = (threadIdx.x & 3) * 16;
  ushort8 o0, o1;
#pragma unroll
  for (int e = 0; e < 8; ++e) { o0[e] = t[sc0 + e][d]; o1[e] = t[sc0 + 8 + e][d]; }
  *(ushort8*)(dst + (size_t)d * 2048 + s0 + sc0) = o0;
  *(ushort8*)(dst + (size_t)d * 2048 + s0 + sc0 + 8) = o1;
}

// ---------------- Flash attention v4: kv-split pairs, in-register softmax, LDS merge ----------------
// 1024 blocks x 4 waves = 4096 waves. Wave pair (half0/half1) splits the kv range of one
// 32-row q-block; merge via LDS once at the end. 4 heads per XCD, LPT (long mt first).
__global__ __launch_bounds__(256, 4) void attn4_k(const u16* __restrict__ Qm,
                                                  const u16* __restrict__ Km,
                                                  const u16* __restrict__ Vtm,
                                                  u16* __restrict__ Om) {
  __shared__ float mrg[2][34][64];
  const int lane = threadIdx.x & 63;
  const int w = threadIdx.x >> 6;
  const int u = w >> 1, half = w & 1;
  const int unit = ((blockIdx.x >> 3) << 1) | u;     // 0..255 within xcd
  const int x = blockIdx.x & 7;                       // xcd stream
  const int bh = 4 * x + (unit & 3);
  const int mt = 63 - (unit >> 2);                    // LPT
  const int b = bh >> 4, hd = bh & 15;
  const int qb = mt * 32;
  const int q32 = lane & 31, h = lane >> 5;
  const int nt = (mt >> 1) + 1;
  const int t0 = half ? (nt >> 1) : 0;
  const int t1 = half ? nt : (nt >> 1);

  const u16* Qp = Qm + ((size_t)bh << 17);
  const u16* Kp = Km + ((size_t)bh << 17);
  const u16* Vtp = Vtm + ((size_t)bh << 17);

  // Q fragments (B-operand): lane holds Q[qb+q32][16ks + 8h .. +7]
  const u16* qrow = Qp + ((size_t)(qb + q32) << 6) + 8 * h;
  short8 qf[4];
#pragma unroll
  for (int ks = 0; ks < 4; ++ks) qf[ks] = *(const short8*)(qrow + 16 * ks);

  f32x16 acc0 = {}, acc1 = {};
  float m_run = -1e30f, l_run = 0.f;
  const int qg = qb + q32;

  for (int kt = t0; kt < t1; ++kt) {
    const int k0 = kt * 64;
    const u16* kbase = Kp + (((size_t)k0 << 6) + 8 * h);

    // ---- QK^T swapped: s0 = S[kv 0..31][q], s1 = S[kv 32..63][q]
    f32x16 s0 = {}, s1 = {};
    __builtin_amdgcn_s_setprio(1);
#pragma unroll
    for (int ks = 0; ks < 4; ++ks) {
      short8 kf = *(const short8*)(kbase + ((size_t)q32 << 6) + 16 * ks);
      s0 = mfma32(kf, qf[ks], s0);
    }
#pragma unroll
    for (int ks = 0; ks < 4; ++ks) {
      short8 kf = *(const short8*)(kbase + ((size_t)(32 + q32) << 6) + 16 * ks);
      s1 = mfma32(kf, qf[ks], s1);
    }
    __builtin_amdgcn_s_setprio(0);

    // ---- V fragment loads issued NOW (consumed after softmax: latency hidden)
    const u16* vbase = Vtp + k0 + 8 * h;
    short8 vfa[4], vfb[4];
#pragma unroll
    for (int ks = 0; ks < 4; ++ks) {
      vfa[ks] = *(const short8*)(vbase + (size_t)q32 * 2048 + 16 * ks);
      vfb[ks] = *(const short8*)(vbase + (size_t)(32 + q32) * 2048 + 16 * ks);
    }

    // ---- causal mask on diagonal tile (only ever true for half==1)
    if (kt == nt - 1) {
#pragma unroll
      for (int r = 0; r < 16; ++r) {
        const int kvl = k0 + (r & 3) + 8 * (r >> 2) + 4 * h;
        s0[r] = (kvl <= qg) ? s0[r] : -1e30f;
        s1[r] = (kvl + 32 <= qg) ? s1[r] : -1e30f;
      }
    }

    // ---- online softmax (lane owns q-row q32; lanes L/L+32 hold kv halves)
    float pmax = s0[0];
#pragma unroll
    for (int r = 1; r < 16; ++r) pmax = fmaxf(pmax, s0[r]);
#pragma unroll
    for (int r = 0; r < 16; ++r) pmax = fmaxf(pmax, s1[r]);
    pmax = fmaxf(pmax, __shfl_xor(pmax, 32));

    if (!__all(pmax <= m_run + 11.5f)) {   // defer-max rescale (rare)
      const float mn = fmaxf(m_run, pmax);
      const float alpha = exp2h(m_run - mn);
      l_run *= alpha;
      m_run = mn;
#pragma unroll
      for (int r = 0; r < 16; ++r) {
        const int row = (r & 3) + 8 * (r >> 2) + 4 * h;
        const float ar = __shfl(alpha, row);
        acc0[r] *= ar; acc1[r] *= ar;
      }
    }

    float rs = 0.f;
#pragma unroll
    for (int r = 0; r < 16; ++r) { s0[r] = exp2h(s0[r] - m_run); rs += s0[r]; }
#pragma unroll
    for (int r = 0; r < 16; ++r) { s1[r] = exp2h(s1[r] - m_run); rs += s1[r]; }
    rs += __shfl_xor(rs, 32);
    l_run += rs;

    // ---- P -> A-fragments in-register (cvt_pk + lane32 exchange)
    short8 pa[4];
#pragma unroll
    for (int t = 0; t < 2; ++t) {
      float p0, p1, p2, p3, p4, p5, p6, p7, p8, p9, pa_, pb_, pc_, pd_, pe_, pf_;
      if (t == 0) {
        p0 = s0[0];  p1 = s0[1];  p2 = s0[2];  p3 = s0[3];
        p4 = s0[4];  p5 = s0[5];  p6 = s0[6];  p7 = s0[7];
        p8 = s0[8];  p9 = s0[9];  pa_ = s0[10]; pb_ = s0[11];
        pc_ = s0[12]; pd_ = s0[13]; pe_ = s0[14]; pf_ = s0[15];
      } else {
        p0 = s1[0];  p1 = s1[1];  p2 = s1[2];  p3 = s1[3];
        p4 = s1[4];  p5 = s1[5];  p6 = s1[6];  p7 = s1[7];
        p8 = s1[8];  p9 = s1[9];  pa_ = s1[10]; pb_ = s1[11];
        pc_ = s1[12]; pd_ = s1[13]; pe_ = s1[14]; pf_ = s1[15];
      }
      const unsigned a0 = cvtpk(p0, p1), a1 = cvtpk(p2, p3);
      const unsigned a2 = cvtpk(p4, p5), a3 = cvtpk(p6, p7);
      const unsigned b0 = cvtpk(p8, p9), b1 = cvtpk(pa_, pb_);
      const unsigned b2 = cvtpk(pc_, pd_), b3 = cvtpk(pe_, pf_);
      const unsigned r0 = __shfl_xor(h ? a0 : a2, 32);
      const unsigned r1 = __shfl_xor(h ? a1 : a3, 32);
      pa[2 * t] = h ? pack4(r0, r1, a2, a3) : pack4(a0, a1, r0, r1);
      const unsigned r2 = __shfl_xor(h ? b0 : b2, 32);
      const unsigned r3 = __shfl_xor(h ? b1 : b3, 32);
      pa[2 * t + 1] = h ? pack4(r2, r3, b2, b3) : pack4(b0, b1, r2, r3);
    }

    // ---- PV
    __builtin_amdgcn_s_setprio(1);
#pragma unroll
    for (int ks = 0; ks < 4; ++ks) {
      acc0 = mfma32(pa[ks], vfa[ks], acc0);
      acc1 = mfma32(pa[ks], vfb[ks], acc1);
    }
    __builtin_amdgcn_s_setprio(0);
  }

  // ---- kv-split merge: half1 publishes (m, l, acc); half0 combines + stores
  if (half) {
    mrg[u][0][lane] = m_run;
    mrg[u][1][lane] = l_run;
#pragma unroll
    for (int r = 0; r < 16; ++r) {
      mrg[u][2 + r][lane] = acc0[r];
      mrg[u][18 + r][lane] = acc1[r];
    }
  }
  __syncthreads();
  if (!half) {
    const float m_o = mrg[u][0][lane];
    const float l_o = mrg[u][1][lane];
    const float M = fmaxf(m_run, m_o);
    const float ss = exp2h(m_run - M);
    const float so = exp2h(m_o - M);
    const float l_c = l_run * ss + l_o * so;
#pragma unroll
    for (int r = 0; r < 16; ++r) {
      const int row = (r & 3) + 8 * (r >> 2) + 4 * h;
      const float ssr = __shfl(ss, row);
      const float sor = __shfl(so, row);
      const float li = 1.0f / __shfl(l_c, row);
      const float o0 = (acc0[r] * ssr + mrg[u][2 + r][lane] * sor) * li;
      const float o1 = (acc1[r] * ssr + mrg[u][18 + r][lane] * sor) * li;
      const int q = qb + row;
      const size_t base = ((size_t)(b * 2048 + q) << 10) + hd * 64 + q32;
      Om[base] = f2bf(o0);
      Om[base + 32] = f2bf(o1);
    }
  }
}

extern "C" void kernel_launch(void* const* d_in, const int* in_sizes, int n_in,
                              void* d_out, int out_size, void* d_ws, size_t ws_size,
                              hipStream_t stream) {
  const float* x        = (const float*)d_in[0];
  const float* rope_cos = (const float*)d_in[1];
  const float* rope_sin = (const float*)d_in[2];
  const float* Wqkv     = (const float*)d_in[3];
  const float* bqkv     = (const float*)d_in[4];
  const float* Wout     = (const float*)d_in[5];
  const float* bout     = (const float*)d_in[6];
  float* out = (float*)d_out;
  char* ws = (char*)d_ws;

  u16* Xb      = (u16*)(ws);                  //  8,388,608 B : x bf16 [4096][1024]
  u16* WqkvT   = (u16*)(ws + 8388608);        //  6,291,456 B : Wqkv^T bf16
  u16* WoutT   = (u16*)(ws + 14680064);       //  2,097,152 B : Wout^T bf16
  u16* QKV     = (u16*)(ws + 16777216);       // 25,165,824 B : [3][2][16][2048][64]
  u16* AttnOut = (u16*)(ws + 41943040);       //  8,388,608 B : [4096][1024] bf16
  u16* Vt      = (u16*)(ws + 50331648);       //  8,388,608 B : [32][64][2048] bf16

  cvt_f32_bf16_k<<<dim3(2048), dim3(256), 0, stream>>>(x, Xb, 524288);
  transpose_f32_bf16_k<<<dim3(96, 32), dim3(256), 0, stream>>>(Wqkv, WqkvT, 1024, 3072);
  transpose_f32_bf16_k<<<dim3(32, 32), dim3(256), 0, stream>>>(Wout, WoutT, 1024, 1024);

  gemm_bt_k<0><<<dim3(24, 32), dim3(256), 0, stream>>>(Xb, WqkvT, bqkv, (void*)QKV);

  rope_k<<<dim3(16384), dim3(256), 0, stream>>>(QKV, rope_cos, rope_sin, 4194304);

  u16* Qw = QKV;
  u16* Kw = QKV + (size_t)4194304;
  u16* Vw = QKV + (size_t)8388608;
  vtrans_k<<<dim3(32, 32), dim3(256), 0, stream>>>(Vw, Vt);
  attn4_k<<<dim3(1024), dim3(256), 0, stream>>>(Qw, Kw, Vt, AttnOut);

  gemm_bt_k<1><<<dim3(8, 32), dim3(256), 0, stream>>>(AttnOut, WoutT, bout, out);
}

// Round 6
// 151.919 us; speedup vs baseline: 1.3223x; 1.2962x over previous
//
#include <hip/hip_runtime.h>
#include <hip/hip_bf16.h>

typedef unsigned short u16;
typedef __attribute__((ext_vector_type(4))) float f32x4;
typedef __attribute__((ext_vector_type(16))) float f32x16;
typedef __attribute__((ext_vector_type(8))) short short8;
typedef __attribute__((ext_vector_type(8))) unsigned short ushort8;

__device__ __forceinline__ u16 f2bf(float f) {
  union { float f; unsigned u; } v; v.f = f;
  unsigned r = v.u + 0x7fffu + ((v.u >> 16) & 1u);
  return (u16)(r >> 16);
}
__device__ __forceinline__ float b2f(u16 h) {
  union { unsigned u; float f; } v; v.u = ((unsigned)h) << 16;
  return v.f;
}
__device__ __forceinline__ f32x4 mfma16(short8 a, short8 b, f32x4 c) {
  return __builtin_amdgcn_mfma_f32_16x16x32_bf16(a, b, c, 0, 0, 0);
}
__device__ __forceinline__ f32x16 mfma32(short8 a, short8 b, f32x16 c) {
  return __builtin_amdgcn_mfma_f32_32x32x16_bf16(a, b, c, 0, 0, 0);
}
__device__ __forceinline__ unsigned cvtpk(float a, float b) {
  unsigned r;
  asm("v_cvt_pk_bf16_f32 %0, %1, %2" : "=v"(r) : "v"(a), "v"(b));
  return r;
}
__device__ __forceinline__ short8 pack4(unsigned w0, unsigned w1, unsigned w2, unsigned w3) {
  union { unsigned u[4]; short8 s; } t;
  t.u[0] = w0; t.u[1] = w1; t.u[2] = w2; t.u[3] = w3;
  return t.s;
}
__device__ __forceinline__ float exp2h(float x) { return __builtin_amdgcn_exp2f(x); }

// ---------------- prep: fp32 -> bf16 convert ----------------
__global__ __launch_bounds__(256) void cvt_f32_bf16_k(const float* __restrict__ in,
                                                      u16* __restrict__ out, int n8) {
  int t = blockIdx.x * 256 + threadIdx.x;
  if (t >= n8) return;
  const float4* p = (const float4*)(in + (size_t)t * 8);
  float4 a = p[0], b = p[1];
  ushort8 o;
  o[0] = f2bf(a.x); o[1] = f2bf(a.y); o[2] = f2bf(a.z); o[3] = f2bf(a.w);
  o[4] = f2bf(b.x); o[5] = f2bf(b.y); o[6] = f2bf(b.z); o[7] = f2bf(b.w);
  *(ushort8*)(out + (size_t)t * 8) = o;
}

// ---------------- prep: transpose fp32 [R][C] -> bf16 [C][R] ----------------
__global__ __launch_bounds__(256) void transpose_f32_bf16_k(const float* __restrict__ in,
                                                            u16* __restrict__ out, int R, int C) {
  __shared__ float tile[32][33];
  int bc = blockIdx.x * 32, br = blockIdx.y * 32;
  int tx = threadIdx.x & 31, ty = threadIdx.x >> 5;
#pragma unroll
  for (int p = 0; p < 4; ++p)
    tile[ty + p * 8][tx] = in[(size_t)(br + ty + p * 8) * C + bc + tx];
  __syncthreads();
#pragma unroll
  for (int p = 0; p < 4; ++p)
    out[(size_t)(bc + ty + p * 8) * R + br + tx] = f2bf(tile[tx][ty + p * 8]);
}

// ---------------- GEMM (m97 structure): C[M][N] = A[M][K=1024] * Bt[N][K=1024]^T ----------------
template <int MODE>
__global__ __launch_bounds__(256) void gemm_bt_k(const u16* __restrict__ A,
                                                 const u16* __restrict__ Bt,
                                                 const float* __restrict__ bias,
                                                 void* __restrict__ Cout) {
  __shared__ __align__(16) u16 As[128 * 32];
  __shared__ __align__(16) u16 Bs[128 * 32];
  const int tid = threadIdx.x, lane = tid & 63, w = tid >> 6;
  const int wr = w >> 1, wc = w & 1, g = lane >> 4, c16 = lane & 15;
  const int rowBase = blockIdx.y * 128, colBase = blockIdx.x * 128;
  f32x4 acc[4][4] = {};
  const int e0 = (w * 2 + 0) * 512 + lane * 8;
  const int e1 = (w * 2 + 1) * 512 + lane * 8;
  const u16* Ag0 = A + (size_t)(rowBase + (e0 >> 5)) * 1024 + (e0 & 31);
  const u16* Ag1 = A + (size_t)(rowBase + (e1 >> 5)) * 1024 + (e1 & 31);
  const u16* Bg0 = Bt + (size_t)(colBase + (e0 >> 5)) * 1024 + (e0 & 31);
  const u16* Bg1 = Bt + (size_t)(colBase + (e1 >> 5)) * 1024 + (e1 & 31);
  u16* As0 = As + (w * 2 + 0) * 512;
  u16* As1 = As + (w * 2 + 1) * 512;
  u16* Bs0 = Bs + (w * 2 + 0) * 512;
  u16* Bs1 = Bs + (w * 2 + 1) * 512;
  for (int k0 = 0; k0 < 1024; k0 += 32) {
    __builtin_amdgcn_global_load_lds((const __attribute__((address_space(1))) void*)(Ag0 + k0),
                                     (__attribute__((address_space(3))) void*)As0, 16, 0, 0);
    __builtin_amdgcn_global_load_lds((const __attribute__((address_space(1))) void*)(Ag1 + k0),
                                     (__attribute__((address_space(3))) void*)As1, 16, 0, 0);
    __builtin_amdgcn_global_load_lds((const __attribute__((address_space(1))) void*)(Bg0 + k0),
                                     (__attribute__((address_space(3))) void*)Bs0, 16, 0, 0);
    __builtin_amdgcn_global_load_lds((const __attribute__((address_space(1))) void*)(Bg1 + k0),
                                     (__attribute__((address_space(3))) void*)Bs1, 16, 0, 0);
    asm volatile("s_waitcnt vmcnt(0)" ::: "memory");
    __syncthreads();
    short8 af[4], bfr[4];
#pragma unroll
    for (int t = 0; t < 4; ++t)
      af[t] = *(const short8*)(As + ((wr * 64 + t * 16 + c16) * 32 + g * 8));
#pragma unroll
    for (int t = 0; t < 4; ++t)
      bfr[t] = *(const short8*)(Bs + ((wc * 64 + t * 16 + c16) * 32 + g * 8));
#pragma unroll
    for (int i = 0; i < 4; ++i)
#pragma unroll
      for (int j = 0; j < 4; ++j) acc[i][j] = mfma16(af[i], bfr[j], acc[i][j]);
    __syncthreads();
  }
#pragma unroll
  for (int i = 0; i < 4; ++i) {
    int mbase = rowBase + wr * 64 + i * 16 + 4 * g;
#pragma unroll
    for (int j = 0; j < 4; ++j) {
      int n = colBase + wc * 64 + j * 16 + c16;
      float bv = bias[n];
#pragma unroll
      for (int r = 0; r < 4; ++r) {
        float v = acc[i][j][r] + bv;
        int m = mbase + r;
        if (MODE == 0) {
          int which = n >> 10, hh = (n >> 6) & 15, d = n & 63;
          int bb = m >> 11, s = m & 2047;
          ((u16*)Cout)[((size_t)(((which * 2 + bb) * 16 + hh) * 2048 + s) << 6) + d] = f2bf(v);
        } else {
          ((float*)Cout)[(size_t)m * 1024 + n] = v;
        }
      }
    }
  }
}

// ---------------- RoPE in place on Q and K; Q additionally pre-scaled by 0.125*log2(e) ----------------
__global__ __launch_bounds__(256) void rope_k(u16* __restrict__ qk, const float* __restrict__ cosT,
                                              const float* __restrict__ sinT, int npairs) {
  int p = blockIdx.x * 256 + threadIdx.x;
  if (p >= npairs) return;
  size_t E = (size_t)p * 2;
  int i = (int)((E >> 1) & 31);
  int s = (int)((E >> 6) & 2047);
  const float qs = (p < 2097152) ? 0.18033688f : 1.0f;  // 0.125 * log2(e) on Q slab
  u16* ptr = qk + E;
  float xe = b2f(ptr[0]), xo = b2f(ptr[1]);
  float c = cosT[s * 32 + i], sn = sinT[s * 32 + i];
  ptr[0] = f2bf((xe * c - xo * sn) * qs);
  ptr[1] = f2bf((xe * sn + xo * c) * qs);
}

// ---------------- V [bh][s][64] -> Vt [bh][64][s] (bf16) ----------------
__global__ __launch_bounds__(256) void vtrans_k(const u16* __restrict__ V, u16* __restrict__ Vt) {
  __shared__ u16 t[64][72];
  const int bh = blockIdx.y, s0 = blockIdx.x * 64;
  const u16* src = V + ((size_t)bh << 17);
  u16* dst = Vt + ((size_t)bh << 17);
  const int r = threadIdx.x >> 2, c0 = (threadIdx.x & 3) * 16;
  *(short8*)&t[r][c0] = *(const short8*)(src + (size_t)(s0 + r) * 64 + c0);
  *(short8*)&t[r][c0 + 8] = *(const short8*)(src + (size_t)(s0 + r) * 64 + c0 + 8);
  __syncthreads();
  const int d = threadIdx.x >> 2, sc0 = (threadIdx.x & 3) * 16;
  ushort8 o0, o1;
#pragma unroll
  for (int e = 0; e < 8; ++e) { o0[e] = t[sc0 + e][d]; o1[e] = t[sc0 + 8 + e][d]; }
  *(ushort8*)(dst + (size_t)d * 2048 + s0 + sc0) = o0;
  *(ushort8*)(dst + (size_t)d * 2048 + s0 + sc0 + 8) = o1;
}

// ---------------- Flash attention v5: LDS-staged K/Vt, 32x32 swapped QK^T, in-reg softmax ----------------
// 1024 blocks x 128 threads (2 waves). Block = 64 q-rows (wave w owns 32), kv tiles of 64.
// Wave0 stages K tile, wave1 stages Vt tile (global_load_lds w16, pre-swizzled source).
// Swizzle: LDS[row][blk] = global[row][blk ^ (row&7)], 16B blocks, rows of 128B.
__global__ __launch_bounds__(128, 4) void attn5_k(const u16* __restrict__ Qm,
                                                  const u16* __restrict__ Km,
                                                  const u16* __restrict__ Vtm,
                                                  u16* __restrict__ Om) {
  __shared__ __align__(16) u16 Klds[2][4096];   // [64 kv][64 d], swizzled
  __shared__ __align__(16) u16 Vlds[2][4096];   // [64 d][64 kv], swizzled

  const int lane = threadIdx.x & 63;
  const int w = threadIdx.x >> 6;                 // 0..1
  const int x = blockIdx.x & 7;                   // xcd stream
  const int idx = blockIdx.x >> 3;                // 0..127
  const int bh = 4 * x + (idx & 3);               // 4 heads per XCD
  const int qmb = 31 - (idx >> 2);                // LPT: heavy macro-tiles first
  const int b = bh >> 4, hd = bh & 15;
  const int qb = qmb * 64 + w * 32;               // this wave's 32 q-rows
  const int q32 = lane & 31, h = lane >> 5;
  const int nt = qmb + 1;                         // kv tiles of 64

  const u16* Qp = Qm + ((size_t)bh << 17);
  const u16* Kp = Km + ((size_t)bh << 17);
  const u16* Vtp = Vtm + ((size_t)bh << 17);

  // Q fragments (B-operand): lane holds Q[qb+q32][16ks + 8h .. +7]
  const u16* qrow = Qp + ((size_t)(qb + q32) << 6) + 8 * h;
  short8 qf[4];
#pragma unroll
  for (int ks = 0; ks < 4; ++ks) qf[ks] = *(const short8*)(qrow + 16 * ks);

  f32x16 acc0 = {}, acc1 = {};
  float m_run = -1e30f, l_run = 0.f;
  const int qg = qb + q32;
  const int r8 = lane >> 3, blk = lane & 7;
  const int swz = q32 & 7;

  auto stage = [&](int buf, int k0) {
#pragma unroll
    for (int i = 0; i < 8; ++i) {
      const int row = i * 8 + r8;
      const int sblk = blk ^ (row & 7);
      if (w == 0) {
        const u16* src = Kp + ((size_t)(k0 + row) << 6) + sblk * 8;
        __builtin_amdgcn_global_load_lds(
            (const __attribute__((address_space(1))) void*)src,
            (__attribute__((address_space(3))) void*)(&Klds[buf][i * 512]), 16, 0, 0);
      } else {
        const u16* src = Vtp + ((size_t)row << 11) + k0 + sblk * 8;
        __builtin_amdgcn_global_load_lds(
            (const __attribute__((address_space(1))) void*)src,
            (__attribute__((address_space(3))) void*)(&Vlds[buf][i * 512]), 16, 0, 0);
      }
    }
  };

  stage(0, 0);
  asm volatile("s_waitcnt vmcnt(0)" ::: "memory");
  __syncthreads();

  for (int kt = 0; kt < nt; ++kt) {
    const int cur = kt & 1;
    if (kt + 1 < nt) stage(cur ^ 1, (kt + 1) * 64);

    const u16* Kb = &Klds[cur][0];
    const u16* Vb = &Vlds[cur][0];
    const int k0 = kt * 64;

    // ---- QK^T swapped: s0 = S[kv 0..31][q], s1 = S[kv 32..63][q]
    f32x16 s0 = {}, s1 = {};
    __builtin_amdgcn_s_setprio(1);
#pragma unroll
    for (int ks = 0; ks < 4; ++ks) {
      const int cb = ((2 * ks + h) ^ swz) * 8;
      short8 kf0 = *(const short8*)(Kb + q32 * 64 + cb);
      short8 kf1 = *(const short8*)(Kb + (32 + q32) * 64 + cb);
      s0 = mfma32(kf0, qf[ks], s0);
      s1 = mfma32(kf1, qf[ks], s1);
    }
    __builtin_amdgcn_s_setprio(0);

    // ---- V fragments issued early (consumed after softmax)
    short8 vfa[4], vfb[4];
#pragma unroll
    for (int ks = 0; ks < 4; ++ks) {
      const int cb = ((2 * ks + h) ^ swz) * 8;
      vfa[ks] = *(const short8*)(Vb + q32 * 64 + cb);
      vfb[ks] = *(const short8*)(Vb + (32 + q32) * 64 + cb);
    }

    // ---- causal mask on the diagonal tile
    if (kt == nt - 1) {
#pragma unroll
      for (int r = 0; r < 16; ++r) {
        const int kvl = k0 + (r & 3) + 8 * (r >> 2) + 4 * h;
        s0[r] = (kvl <= qg) ? s0[r] : -1e30f;
        s1[r] = (kvl + 32 <= qg) ? s1[r] : -1e30f;
      }
    }

    // ---- online softmax (lane owns q-row q32; lanes L/L+32 hold kv halves)
    float pmax = s0[0];
#pragma unroll
    for (int r = 1; r < 16; ++r) pmax = fmaxf(pmax, s0[r]);
#pragma unroll
    for (int r = 0; r < 16; ++r) pmax = fmaxf(pmax, s1[r]);
    pmax = fmaxf(pmax, __shfl_xor(pmax, 32));

    if (!__all(pmax <= m_run + 11.5f)) {   // defer-max rescale (rare)
      const float mn = fmaxf(m_run, pmax);
      const float alpha = exp2h(m_run - mn);
      l_run *= alpha;
      m_run = mn;
#pragma unroll
      for (int r = 0; r < 16; ++r) {
        const int row = (r & 3) + 8 * (r >> 2) + 4 * h;
        const float ar = __shfl(alpha, row);
        acc0[r] *= ar; acc1[r] *= ar;
      }
    }

    float rs = 0.f;
#pragma unroll
    for (int r = 0; r < 16; ++r) { s0[r] = exp2h(s0[r] - m_run); rs += s0[r]; }
#pragma unroll
    for (int r = 0; r < 16; ++r) { s1[r] = exp2h(s1[r] - m_run); rs += s1[r]; }
    rs += __shfl_xor(rs, 32);
    l_run += rs;

    // ---- P -> A-fragments in-register (cvt_pk + lane32 exchange)
    short8 pa[4];
#pragma unroll
    for (int t = 0; t < 2; ++t) {
      float p0, p1, p2, p3, p4, p5, p6, p7, p8, p9, pa_, pb_, pc_, pd_, pe_, pf_;
      if (t == 0) {
        p0 = s0[0];  p1 = s0[1];  p2 = s0[2];  p3 = s0[3];
        p4 = s0[4];  p5 = s0[5];  p6 = s0[6];  p7 = s0[7];
        p8 = s0[8];  p9 = s0[9];  pa_ = s0[10]; pb_ = s0[11];
        pc_ = s0[12]; pd_ = s0[13]; pe_ = s0[14]; pf_ = s0[15];
      } else {
        p0 = s1[0];  p1 = s1[1];  p2 = s1[2];  p3 = s1[3];
        p4 = s1[4];  p5 = s1[5];  p6 = s1[6];  p7 = s1[7];
        p8 = s1[8];  p9 = s1[9];  pa_ = s1[10]; pb_ = s1[11];
        pc_ = s1[12]; pd_ = s1[13]; pe_ = s1[14]; pf_ = s1[15];
      }
      const unsigned a0 = cvtpk(p0, p1), a1 = cvtpk(p2, p3);
      const unsigned a2 = cvtpk(p4, p5), a3 = cvtpk(p6, p7);
      const unsigned b0 = cvtpk(p8, p9), b1 = cvtpk(pa_, pb_);
      const unsigned b2 = cvtpk(pc_, pd_), b3 = cvtpk(pe_, pf_);
      const unsigned r0 = __shfl_xor(h ? a0 : a2, 32);
      const unsigned r1 = __shfl_xor(h ? a1 : a3, 32);
      pa[2 * t] = h ? pack4(r0, r1, a2, a3) : pack4(a0, a1, r0, r1);
      const unsigned r2 = __shfl_xor(h ? b0 : b2, 32);
      const unsigned r3 = __shfl_xor(h ? b1 : b3, 32);
      pa[2 * t + 1] = h ? pack4(r2, r3, b2, b3) : pack4(b0, b1, r2, r3);
    }

    // ---- PV
    __builtin_amdgcn_s_setprio(1);
#pragma unroll
    for (int ks = 0; ks < 4; ++ks) {
      acc0 = mfma32(pa[ks], vfa[ks], acc0);
      acc1 = mfma32(pa[ks], vfb[ks], acc1);
    }
    __builtin_amdgcn_s_setprio(0);

    asm volatile("s_waitcnt vmcnt(0)" ::: "memory");
    __syncthreads();
  }

  // ---- epilogue: divide by l (per-row broadcast) and store
#pragma unroll
  for (int r = 0; r < 16; ++r) {
    const int row = (r & 3) + 8 * (r >> 2) + 4 * h;
    const float li = 1.0f / __shfl(l_run, row);
    const int q = qb + row;
    const size_t base = ((size_t)(b * 2048 + q) << 10) + hd * 64 + q32;
    Om[base] = f2bf(acc0[r] * li);
    Om[base + 32] = f2bf(acc1[r] * li);
  }
}

extern "C" void kernel_launch(void* const* d_in, const int* in_sizes, int n_in,
                              void* d_out, int out_size, void* d_ws, size_t ws_size,
                              hipStream_t stream) {
  const float* x        = (const float*)d_in[0];
  const float* rope_cos = (const float*)d_in[1];
  const float* rope_sin = (const float*)d_in[2];
  const float* Wqkv     = (const float*)d_in[3];
  const float* bqkv     = (const float*)d_in[4];
  const float* Wout     = (const float*)d_in[5];
  const float* bout     = (const float*)d_in[6];
  float* out = (float*)d_out;
  char* ws = (char*)d_ws;

  u16* Xb      = (u16*)(ws);                  //  8,388,608 B : x bf16 [4096][1024]
  u16* WqkvT   = (u16*)(ws + 8388608);        //  6,291,456 B : Wqkv^T bf16
  u16* WoutT   = (u16*)(ws + 14680064);       //  2,097,152 B : Wout^T bf16
  u16* QKV     = (u16*)(ws + 16777216);       // 25,165,824 B : [3][2][16][2048][64]
  u16* AttnOut = (u16*)(ws + 41943040);       //  8,388,608 B : [4096][1024] bf16
  u16* Vt      = (u16*)(ws + 50331648);       //  8,388,608 B : [32][64][2048] bf16

  cvt_f32_bf16_k<<<dim3(2048), dim3(256), 0, stream>>>(x, Xb, 524288);
  transpose_f32_bf16_k<<<dim3(96, 32), dim3(256), 0, stream>>>(Wqkv, WqkvT, 1024, 3072);
  transpose_f32_bf16_k<<<dim3(32, 32), dim3(256), 0, stream>>>(Wout, WoutT, 1024, 1024);

  gemm_bt_k<0><<<dim3(24, 32), dim3(256), 0, stream>>>(Xb, WqkvT, bqkv, (void*)QKV);

  rope_k<<<dim3(16384), dim3(256), 0, stream>>>(QKV, rope_cos, rope_sin, 4194304);

  u16* Qw = QKV;
  u16* Kw = QKV + (size_t)4194304;
  u16* Vw = QKV + (size_t)8388608;
  vtrans_k<<<dim3(32, 32), dim3(256), 0, stream>>>(Vw, Vt);
  attn5_k<<<dim3(1024), dim3(128), 0, stream>>>(Qw, Kw, Vt, AttnOut);

  gemm_bt_k<1><<<dim3(8, 32), dim3(256), 0, stream>>>(AttnOut, WoutT, bout, out);
}